// Round 7
// baseline (155.646 us; speedup 1.0000x reference)
//
#include <hip/hip_runtime.h>
#include <hip/hip_bf16.h>

// ============================================================================
// ROUND 7: ATTN INSTRUMENTATION BUILD (the R2 trick, now aimed at attn).
//   Base = best-known config: R1 inner loop, unroll 4, no prefetch, no
//   ones-MFMA, no launch_bounds clamp.  Phase-1 repeated x4 (O and ls both
//   scale x4 -> normalization cancels; pointers laundered per rep).
//   Amplified attn ~55-62us -> top-1 dispatch WITH counters.
// ============================================================================

#define B_ 8
#define D_ 128
#define NH 8
#define L_ 1024
#define DK 16

#define REPS_ATTN 4

typedef __attribute__((ext_vector_type(4))) short s4;
typedef __attribute__((ext_vector_type(4))) float f4;

static __device__ __forceinline__ unsigned short f2bf(float f) {
    __hip_bfloat16 h = __float2bfloat16(f);
    return *reinterpret_cast<unsigned short*>(&h);
}
static __device__ __forceinline__ unsigned pack2(float a, float b) {
    return (unsigned)f2bf(a) | ((unsigned)f2bf(b) << 16);
}
static __device__ __forceinline__ s4 pack4(float a, float b, float c, float d) {
    union { unsigned u[2]; s4 v; } un;
    un.u[0] = pack2(a, b);
    un.u[1] = pack2(c, d);
    return un.v;
}

// exp2 via native trans op (K pre-scaled by 0.25*log2(e) so exp(S)=exp2(S')).
static __device__ __forceinline__ float fexp2(float x) {
#if __has_builtin(__builtin_amdgcn_exp2f)
    return __builtin_amdgcn_exp2f(x);
#else
    float r; asm("v_exp_f32 %0, %1" : "=v"(r) : "v"(x)); return r;
#endif
}

// 16x16x16 bf16 MFMA: D = A*B + C.  A[m=lane&15][k=(lane>>4)*4+jj],
// B[k=(lane>>4)*4+jj][n=lane&15], C/D[row=(lane>>4)*4+reg][col=lane&15].
#if __has_builtin(__builtin_amdgcn_mfma_f32_16x16x16_bf16)
#define MFMA16(a, b, c) __builtin_amdgcn_mfma_f32_16x16x16_bf16(a, b, c, 0, 0, 0)
#elif __has_builtin(__builtin_amdgcn_mfma_f32_16x16x16bf16_1k)
#define MFMA16(a, b, c) __builtin_amdgcn_mfma_f32_16x16x16bf16_1k(a, b, c, 0, 0, 0)
#else
static __device__ __forceinline__ f4 mfma16_asm(s4 a, s4 b, f4 c) {
    f4 d;
    asm volatile("v_mfma_f32_16x16x16_bf16 %0, %1, %2, %3"
                 : "=&v"(d) : "v"(a), "v"(b), "v"(c));
    return d;
}
#define MFMA16(a, b, c) mfma16_asm(a, b, c)
#endif

// ---------------------------------------------------------------------------
// Kernel 1: FUSED QKV projection (unchanged from R3 -- measured ~5us).
// grid (16, 64), block 256.
// ---------------------------------------------------------------------------
__global__ __launch_bounds__(256)
void proj_kernel(const float* __restrict__ x,
                 const float* __restrict__ Wq,
                 const float* __restrict__ Wk,
                 const float* __restrict__ Wv,
                 unsigned short* __restrict__ Qt,
                 unsigned short* __restrict__ Kt,
                 unsigned short* __restrict__ Vt) {
    const int lane = threadIdx.x & 63;
    const int wv   = threadIdx.x >> 6;
    const int m = lane & 15, q = lane >> 4;
    const int bh = blockIdx.y, b = bh >> 3, h = bh & 7;
    const int n0 = (blockIdx.x * 4 + wv) * 16;

    const size_t wrow_off = ((size_t)((h * B_ + b) * DK + m)) * D_;  // A row m
    const float* Wqr = Wq + wrow_off;
    const float* Wkr = Wk + wrow_off;
    const float* Wvr = Wv + wrow_off;
    const float* xb = x + (size_t)b * D_ * L_ + n0 + m;

    f4 aQ = {0.f, 0.f, 0.f, 0.f}, aK = {0.f, 0.f, 0.f, 0.f}, aV = {0.f, 0.f, 0.f, 0.f};
#pragma unroll
    for (int kb = 0; kb < 8; ++kb) {
        const int k4 = kb * 16 + q * 4;

        const float* xc = xb + (size_t)k4 * L_;
        float b0 = xc[0], b1 = xc[L_], b2 = xc[2 * L_], b3 = xc[3 * L_];
        s4 bf = pack4(b0, b1, b2, b3);

        float4 wq = *(const float4*)(Wqr + k4);
        float4 wk = *(const float4*)(Wkr + k4);
        float4 wv4 = *(const float4*)(Wvr + k4);
        s4 fq = pack4(wq.x, wq.y, wq.z, wq.w);
        s4 fk = pack4(wk.x, wk.y, wk.z, wk.w);
        s4 fv = pack4(wv4.x, wv4.y, wv4.z, wv4.w);

        aQ = MFMA16(fq, bf, aQ);
        aK = MFMA16(fk, bf, aK);
        aV = MFMA16(fv, bf, aV);
    }

    // Epilogues.  C layout: [row = q*4 + r][col = m] (row = dk, col = l).
    uint2 uq;
    uq.x = pack2(aQ[0], aQ[1]);
    uq.y = pack2(aQ[2], aQ[3]);
    *(uint2*)(Qt + ((size_t)bh * L_ + n0 + m) * DK + q * 4) = uq;

    const float sc = 0.25f * 1.4426950408889634f;   // 1/sqrt(Dk) * log2(e)
    uint2 uk;
    uk.x = pack2(aK[0] * sc, aK[1] * sc);
    uk.y = pack2(aK[2] * sc, aK[3] * sc);
    *(uint2*)(Kt + ((size_t)bh * L_ + n0 + m) * DK + q * 4) = uk;

    unsigned short* vp = Vt + ((size_t)bh * DK + q * 4) * L_ + n0 + m;
    vp[0]      = f2bf(aV[0]); vp[L_]     = f2bf(aV[1]);
    vp[2 * L_] = f2bf(aV[2]); vp[3 * L_] = f2bf(aV[3]);
}

// ---------------------------------------------------------------------------
// Kernel 2: fused attention + output projection.  BASE = exact R1 inner
// loop (unroll 4).  INSTRUMENTED: phase-1 x REPS_ATTN via laundered rep
// loop; O and ls both scale by REPS -> softmax normalization cancels.
// grid (32, 8), block 1024 = 16 waves (h, ihalf), no clamp.
// ---------------------------------------------------------------------------
__global__ __launch_bounds__(1024)
void attn_out_kernel(const unsigned short* __restrict__ Qt,
                     const unsigned short* __restrict__ Kt,
                     const unsigned short* __restrict__ Vt,
                     const float* __restrict__ Wo,
                     float* __restrict__ out) {
    const int lane = threadIdx.x & 63;
    const int wid  = threadIdx.x >> 6;          // 0..15
    const int m = lane & 15, q = lane >> 4;
    const int b    = blockIdx.y;
    const int jblk = blockIdx.x * 32;

    const int h     = wid & 7;
    const int ihalf = wid >> 3;
    const int bh    = b * NH + h;

    __shared__ unsigned short hls[32][132];     // [l_local][d], 8.25 KB
    __shared__ float red[8][64][12];            // O0(4) O1(4) ls0 ls1

    // ---- Phase 1: partial attention for (head h, i-half ihalf), 32 j-cols
    s4 bk0 = *(const s4*)(Kt + ((size_t)bh * L_ + jblk + m) * DK + q * 4);
    s4 bk1 = *(const s4*)(Kt + ((size_t)bh * L_ + jblk + 16 + m) * DK + q * 4);

    f4 O0 = {0.f, 0.f, 0.f, 0.f}, O1 = {0.f, 0.f, 0.f, 0.f};
    float ls0 = 0.f, ls1 = 0.f;
    const unsigned short* qbase = Qt + (size_t)bh * L_ * DK + q * 4
                                     + (size_t)(ihalf * (L_ / 2)) * DK;
    const unsigned short* vbase = Vt + ((size_t)bh * DK + m) * L_ + q * 4
                                     + ihalf * (L_ / 2);

#pragma unroll 1
    for (int rep = 0; rep < REPS_ATTN; ++rep) {
        const unsigned short* qb = qbase;
        const unsigned short* vb = vbase;
        asm volatile("" : "+v"(qb), "+v"(vb));
#pragma unroll 4
        for (int i0 = 0; i0 < L_ / 2; i0 += 16) {
            s4 aq = *(const s4*)(qb + (size_t)(i0 + m) * DK);
            s4 av = *(const s4*)(vb + i0);

            f4 z = {0.f, 0.f, 0.f, 0.f};
            f4 S0 = MFMA16(aq, bk0, z);     // S[i0+q*4+r][jblk+m]     (*log2e)
            f4 S1 = MFMA16(aq, bk1, z);     // S[i0+q*4+r][jblk+16+m]  (*log2e)

            float p00 = fexp2(S0[0]), p01 = fexp2(S0[1]);
            float p02 = fexp2(S0[2]), p03 = fexp2(S0[3]);
            float p10 = fexp2(S1[0]), p11 = fexp2(S1[1]);
            float p12 = fexp2(S1[2]), p13 = fexp2(S1[3]);
            ls0 += (p00 + p01) + (p02 + p03);
            ls1 += (p10 + p11) + (p12 + p13);

            s4 pb0, pb1;
            pb0[0] = (short)f2bf(p00); pb0[1] = (short)f2bf(p01);
            pb0[2] = (short)f2bf(p02); pb0[3] = (short)f2bf(p03);
            pb1[0] = (short)f2bf(p10); pb1[1] = (short)f2bf(p11);
            pb1[2] = (short)f2bf(p12); pb1[3] = (short)f2bf(p13);

            O0 = MFMA16(av, pb0, O0);       // O[v=q*4+r][col] += V*P
            O1 = MFMA16(av, pb1, O1);
        }
    }

    ls0 += __shfl_xor(ls0, 16, 64);
    ls0 += __shfl_xor(ls0, 32, 64);
    ls1 += __shfl_xor(ls1, 16, 64);
    ls1 += __shfl_xor(ls1, 32, 64);

    if (ihalf) {
        float* r = red[h][lane];
        *(f4*)(r)     = O0;
        *(f4*)(r + 4) = O1;
        r[8] = ls0; r[9] = ls1;
    }
    __syncthreads();
    if (!ihalf) {
        const float* r = red[h][lane];
        f4 P0 = *(const f4*)(r), P1 = *(const f4*)(r + 4);
        O0 += P0; O1 += P1;
        const float inv0 = 1.f / (ls0 + r[8]);   // both x REPS -> cancels
        const float inv1 = 1.f / (ls1 + r[9]);

        // head tile rows l_local = {m, 16+m}, cols d = h*16 + q*4 + r
        uint2 o0, o1;
        o0.x = pack2(O0[0] * inv0, O0[1] * inv0);
        o0.y = pack2(O0[2] * inv0, O0[3] * inv0);
        o1.x = pack2(O1[0] * inv1, O1[1] * inv1);
        o1.y = pack2(O1[2] * inv1, O1[3] * inv1);
        *(uint2*)&hls[m][h * 16 + q * 4]      = o0;
        *(uint2*)&hls[16 + m][h * 16 + q * 4] = o1;
    }
    __syncthreads();

    // ---- Phase 2: wave -> (o-chunk, j-subtile); 8 kb steps, 1 MFMA each
    {
        const int oc = wid & 7, jt = wid >> 3;
        const int o0 = oc * 16;
        const float* Wrow = Wo + ((size_t)b * D_ + o0 + m) * D_;

        f4 acc = {0.f, 0.f, 0.f, 0.f};
#pragma unroll
        for (int kb = 0; kb < 8; ++kb) {
            const int k4 = kb * 16 + q * 4;
            float4 wf = *(const float4*)(Wrow + k4);
            s4 a  = pack4(wf.x, wf.y, wf.z, wf.w);
            s4 bb = *(const s4*)&hls[jt * 16 + m][k4];   // B[k][n=l] = hls[l][k]
            acc = MFMA16(a, bb, acc);
        }

        float* op = out + ((size_t)b * D_ + o0 + q * 4) * L_ + jblk + jt * 16 + m;
        op[0]      = acc[0]; op[L_]     = acc[1];
        op[2 * L_] = acc[2]; op[3 * L_] = acc[3];
    }
}

// ---------------------------------------------------------------------------
extern "C" void kernel_launch(void* const* d_in, const int* in_sizes, int n_in,
                              void* d_out, int out_size, void* d_ws, size_t ws_size,
                              hipStream_t stream) {
    const float* x  = (const float*)d_in[0];
    const float* Wq = (const float*)d_in[1];
    const float* Wk = (const float*)d_in[2];
    const float* Wv = (const float*)d_in[3];
    const float* Wo = (const float*)d_in[4];
    float* out = (float*)d_out;

    const size_t SEG = (size_t)B_ * NH * DK * L_;   // 1,048,576 elements
    unsigned short* Qt = (unsigned short*)d_ws;     // bf16 [bh][l][k], 2 MB
    unsigned short* Kt = Qt + SEG;                  // bf16 [bh][j][k], 2 MB
    unsigned short* Vt = Kt + SEG;                  // bf16 [bh][v][i], 2 MB

    proj_kernel<<<dim3(16, B_ * NH), 256, 0, stream>>>(x, Wq, Wk, Wv, Qt, Kt, Vt);
    attn_out_kernel<<<dim3(32, B_), 1024, 0, stream>>>(Qt, Kt, Vt, Wo, out);
}

// Round 8
// 119.195 us; speedup vs baseline: 1.3058x; 1.3058x over previous
//
#include <hip/hip_runtime.h>
#include <hip/hip_bf16.h>

#define B_ 8
#define D_ 128
#define NH 8
#define L_ 1024
#define DK 16

typedef __attribute__((ext_vector_type(4))) short s4;
typedef __attribute__((ext_vector_type(4))) float f4;

static __device__ __forceinline__ unsigned short f2bf(float f) {
    __hip_bfloat16 h = __float2bfloat16(f);
    return *reinterpret_cast<unsigned short*>(&h);
}
static __device__ __forceinline__ unsigned pack2(float a, float b) {
    return (unsigned)f2bf(a) | ((unsigned)f2bf(b) << 16);
}
static __device__ __forceinline__ s4 pack4(float a, float b, float c, float d) {
    union { unsigned u[2]; s4 v; } un;
    un.u[0] = pack2(a, b);
    un.u[1] = pack2(c, d);
    return un.v;
}

// exp2 via native trans op (K pre-scaled by 0.25*log2(e) so exp(S)=exp2(S')).
static __device__ __forceinline__ float fexp2(float x) {
#if __has_builtin(__builtin_amdgcn_exp2f)
    return __builtin_amdgcn_exp2f(x);
#else
    float r; asm("v_exp_f32 %0, %1" : "=v"(r) : "v"(x)); return r;
#endif
}

// 16x16x16 bf16 MFMA: D = A*B + C.  A[m=lane&15][k=(lane>>4)*4+jj],
// B[k=(lane>>4)*4+jj][n=lane&15], C/D[row=(lane>>4)*4+reg][col=lane&15].
#if __has_builtin(__builtin_amdgcn_mfma_f32_16x16x16_bf16)
#define MFMA16(a, b, c) __builtin_amdgcn_mfma_f32_16x16x16_bf16(a, b, c, 0, 0, 0)
#elif __has_builtin(__builtin_amdgcn_mfma_f32_16x16x16bf16_1k)
#define MFMA16(a, b, c) __builtin_amdgcn_mfma_f32_16x16x16bf16_1k(a, b, c, 0, 0, 0)
#else
static __device__ __forceinline__ f4 mfma16_asm(s4 a, s4 b, f4 c) {
    f4 d;
    asm volatile("v_mfma_f32_16x16x16_bf16 %0, %1, %2, %3"
                 : "=&v"(d) : "v"(a), "v"(b), "v"(c));
    return d;
}
#define MFMA16(a, b, c) mfma16_asm(a, b, c)
#endif

// ---------------------------------------------------------------------------
// Kernel 1: FUSED QKV projection (unchanged from R3 -- measured ~5us).
// One wave computes Q, K, V for a 16-wide l-tile: x fragment loaded+packed
// ONCE, fed to 3 MFMAs.  grid (16, 64), block 256.
// ---------------------------------------------------------------------------
__global__ __launch_bounds__(256)
void proj_kernel(const float* __restrict__ x,
                 const float* __restrict__ Wq,
                 const float* __restrict__ Wk,
                 const float* __restrict__ Wv,
                 unsigned short* __restrict__ Qt,
                 unsigned short* __restrict__ Kt,
                 unsigned short* __restrict__ Vt) {
    const int lane = threadIdx.x & 63;
    const int wv   = threadIdx.x >> 6;
    const int m = lane & 15, q = lane >> 4;
    const int bh = blockIdx.y, b = bh >> 3, h = bh & 7;
    const int n0 = (blockIdx.x * 4 + wv) * 16;

    const size_t wrow_off = ((size_t)((h * B_ + b) * DK + m)) * D_;  // A row m
    const float* Wqr = Wq + wrow_off;
    const float* Wkr = Wk + wrow_off;
    const float* Wvr = Wv + wrow_off;
    const float* xb = x + (size_t)b * D_ * L_ + n0 + m;

    f4 aQ = {0.f, 0.f, 0.f, 0.f}, aK = {0.f, 0.f, 0.f, 0.f}, aV = {0.f, 0.f, 0.f, 0.f};
#pragma unroll
    for (int kb = 0; kb < 8; ++kb) {
        const int k4 = kb * 16 + q * 4;

        const float* xc = xb + (size_t)k4 * L_;
        float b0 = xc[0], b1 = xc[L_], b2 = xc[2 * L_], b3 = xc[3 * L_];
        s4 bf = pack4(b0, b1, b2, b3);

        float4 wq = *(const float4*)(Wqr + k4);
        float4 wk = *(const float4*)(Wkr + k4);
        float4 wv4 = *(const float4*)(Wvr + k4);
        s4 fq = pack4(wq.x, wq.y, wq.z, wq.w);
        s4 fk = pack4(wk.x, wk.y, wk.z, wk.w);
        s4 fv = pack4(wv4.x, wv4.y, wv4.z, wv4.w);

        aQ = MFMA16(fq, bf, aQ);
        aK = MFMA16(fk, bf, aK);
        aV = MFMA16(fv, bf, aV);
    }

    // Epilogues.  C layout: [row = q*4 + r][col = m] (row = dk, col = l).
    uint2 uq;
    uq.x = pack2(aQ[0], aQ[1]);
    uq.y = pack2(aQ[2], aQ[3]);
    *(uint2*)(Qt + ((size_t)bh * L_ + n0 + m) * DK + q * 4) = uq;

    const float sc = 0.25f * 1.4426950408889634f;   // 1/sqrt(Dk) * log2(e)
    uint2 uk;
    uk.x = pack2(aK[0] * sc, aK[1] * sc);
    uk.y = pack2(aK[2] * sc, aK[3] * sc);
    *(uint2*)(Kt + ((size_t)bh * L_ + n0 + m) * DK + q * 4) = uk;

    unsigned short* vp = Vt + ((size_t)bh * DK + q * 4) * L_ + n0 + m;
    vp[0]      = f2bf(aV[0]); vp[L_]     = f2bf(aV[1]);
    vp[2 * L_] = f2bf(aV[2]); vp[3 * L_] = f2bf(aV[3]);
}

// ---------------------------------------------------------------------------
// Kernel 2: fused attention + output projection.
// R7 counters on the amplified build: MfmaUtil 15.7%, VALUBusy 37%,
// Occupancy 42%, VGPR 48, HBM 3% -> ~50% issue bubbles, latency-bound at
// 1 block/CU (4 waves/SIMD).  Fix: DOUBLE blocks/CU via 16-wide j-tiles,
// grid (64,8), 512 blocks -> 2 blocks/CU -> 8 waves/SIMD.  NO launch_bounds
// min-waves clamp (R3's failure was the clamp's VGPR=28 starvation, not the
// geometry: VGPR=48 fits 8 waves/SIMD unclamped).  Inner loop byte-identical
// to the R1/R7-calibrated form (unroll 4, VALU ls, shfl reduce).
// Phase 1: wave (h, ihalf): 32 iters of {S = Q*K (1 MFMA), p = exp2(S),
//   O += V*p (1 MFMA), ls += sum p}.  Partials additive -> LDS merge.
// Phase 2: waves 0-7: out[b][o0..o0+15][jblk..+15] = Wo[b] @ hls.
// ---------------------------------------------------------------------------
__global__ __launch_bounds__(1024)
void attn_out_kernel(const unsigned short* __restrict__ Qt,
                     const unsigned short* __restrict__ Kt,
                     const unsigned short* __restrict__ Vt,
                     const float* __restrict__ Wo,
                     float* __restrict__ out) {
    const int lane = threadIdx.x & 63;
    const int wid  = threadIdx.x >> 6;          // 0..15
    const int m = lane & 15, q = lane >> 4;
    const int b    = blockIdx.y;
    const int jblk = blockIdx.x * 16;

    const int h     = wid & 7;
    const int ihalf = wid >> 3;
    const int bh    = b * NH + h;

    __shared__ unsigned short hls[16][132];     // [l_local][d], 4.125 KB
    __shared__ float red[8][64][8];             // O(4) + ls(1), 16 KB

    // ---- Phase 1: partial attention for (head h, i-half ihalf), 16 j-cols
    s4 bk = *(const s4*)(Kt + ((size_t)bh * L_ + jblk + m) * DK + q * 4);

    f4 O = {0.f, 0.f, 0.f, 0.f};
    float ls = 0.f;
    const unsigned short* qbase = Qt + (size_t)bh * L_ * DK + q * 4
                                     + (size_t)(ihalf * (L_ / 2)) * DK;
    const unsigned short* vbase = Vt + ((size_t)bh * DK + m) * L_ + q * 4
                                     + ihalf * (L_ / 2);

#pragma unroll 4
    for (int i0 = 0; i0 < L_ / 2; i0 += 16) {
        s4 aq = *(const s4*)(qbase + (size_t)(i0 + m) * DK);
        s4 av = *(const s4*)(vbase + i0);

        f4 z = {0.f, 0.f, 0.f, 0.f};
        f4 S = MFMA16(aq, bk, z);       // S[i0+q*4+r][jblk+m]  (*log2e)

        float p0 = fexp2(S[0]), p1 = fexp2(S[1]);
        float p2 = fexp2(S[2]), p3 = fexp2(S[3]);
        ls += (p0 + p1) + (p2 + p3);

        s4 pb;
        pb[0] = (short)f2bf(p0); pb[1] = (short)f2bf(p1);
        pb[2] = (short)f2bf(p2); pb[3] = (short)f2bf(p3);

        O = MFMA16(av, pb, O);          // O[v=q*4+r][jblk+m] += V*P
    }

    ls += __shfl_xor(ls, 16, 64);
    ls += __shfl_xor(ls, 32, 64);

    if (ihalf) {
        float* r = red[h][lane];
        *(f4*)(r) = O;
        r[4] = ls;
    }
    __syncthreads();
    if (!ihalf) {
        const float* r = red[h][lane];
        f4 P = *(const f4*)(r);
        O += P;
        const float inv = 1.f / (ls + r[4]);

        // head tile row l_local = m, cols d = h*16 + q*4 + r
        uint2 o0;
        o0.x = pack2(O[0] * inv, O[1] * inv);
        o0.y = pack2(O[2] * inv, O[3] * inv);
        *(uint2*)&hls[m][h * 16 + q * 4] = o0;
    }
    __syncthreads();

    // ---- Phase 2: waves 0-7 -> o-chunk each; 8 kb steps, 1 MFMA each
    if (wid < 8) {
        const int o0 = wid * 16;
        const float* Wrow = Wo + ((size_t)b * D_ + o0 + m) * D_;

        f4 acc = {0.f, 0.f, 0.f, 0.f};
#pragma unroll
        for (int kb = 0; kb < 8; ++kb) {
            const int k4 = kb * 16 + q * 4;
            float4 wf = *(const float4*)(Wrow + k4);
            s4 a  = pack4(wf.x, wf.y, wf.z, wf.w);
            s4 bb = *(const s4*)&hls[m][k4];     // B[k][n=l] = hls[l][k]
            acc = MFMA16(a, bb, acc);
        }

        float* op = out + ((size_t)b * D_ + o0 + q * 4) * L_ + jblk + m;
        op[0]      = acc[0]; op[L_]     = acc[1];
        op[2 * L_] = acc[2]; op[3 * L_] = acc[3];
    }
}

// ---------------------------------------------------------------------------
extern "C" void kernel_launch(void* const* d_in, const int* in_sizes, int n_in,
                              void* d_out, int out_size, void* d_ws, size_t ws_size,
                              hipStream_t stream) {
    const float* x  = (const float*)d_in[0];
    const float* Wq = (const float*)d_in[1];
    const float* Wk = (const float*)d_in[2];
    const float* Wv = (const float*)d_in[3];
    const float* Wo = (const float*)d_in[4];
    float* out = (float*)d_out;

    const size_t SEG = (size_t)B_ * NH * DK * L_;   // 1,048,576 elements
    unsigned short* Qt = (unsigned short*)d_ws;     // bf16 [bh][l][k], 2 MB
    unsigned short* Kt = Qt + SEG;                  // bf16 [bh][j][k], 2 MB
    unsigned short* Vt = Kt + SEG;                  // bf16 [bh][v][i], 2 MB

    proj_kernel<<<dim3(16, B_ * NH), 256, 0, stream>>>(x, Wq, Wk, Wv, Qt, Kt, Vt);
    attn_out_kernel<<<dim3(64, B_), 1024, 0, stream>>>(Qt, Kt, Vt, Wo, out);
}

// Round 9
// 99.588 us; speedup vs baseline: 1.5629x; 1.1969x over previous
//
#include <hip/hip_runtime.h>
#include <hip/hip_bf16.h>

#define B_ 8
#define D_ 128
#define NH 8
#define L_ 1024
#define DK 16

typedef __attribute__((ext_vector_type(4))) short s4;
typedef __attribute__((ext_vector_type(4))) float f4;

static __device__ __forceinline__ unsigned short f2bf(float f) {
    __hip_bfloat16 h = __float2bfloat16(f);
    return *reinterpret_cast<unsigned short*>(&h);
}
static __device__ __forceinline__ unsigned pack2(float a, float b) {
    return (unsigned)f2bf(a) | ((unsigned)f2bf(b) << 16);
}
static __device__ __forceinline__ s4 pack4(float a, float b, float c, float d) {
    union { unsigned u[2]; s4 v; } un;
    un.u[0] = pack2(a, b);
    un.u[1] = pack2(c, d);
    return un.v;
}

// exp2 via native trans op (K pre-scaled by 0.25*log2(e) so exp(S)=exp2(S')).
static __device__ __forceinline__ float fexp2(float x) {
#if __has_builtin(__builtin_amdgcn_exp2f)
    return __builtin_amdgcn_exp2f(x);
#else
    float r; asm("v_exp_f32 %0, %1" : "=v"(r) : "v"(x)); return r;
#endif
}

// 16x16x16 bf16 MFMA: D = A*B + C.  A[m=lane&15][k=(lane>>4)*4+jj],
// B[k=(lane>>4)*4+jj][n=lane&15], C/D[row=(lane>>4)*4+reg][col=lane&15].
#if __has_builtin(__builtin_amdgcn_mfma_f32_16x16x16_bf16)
#define MFMA16(a, b, c) __builtin_amdgcn_mfma_f32_16x16x16_bf16(a, b, c, 0, 0, 0)
#elif __has_builtin(__builtin_amdgcn_mfma_f32_16x16x16bf16_1k)
#define MFMA16(a, b, c) __builtin_amdgcn_mfma_f32_16x16x16bf16_1k(a, b, c, 0, 0, 0)
#else
static __device__ __forceinline__ f4 mfma16_asm(s4 a, s4 b, f4 c) {
    f4 d;
    asm volatile("v_mfma_f32_16x16x16_bf16 %0, %1, %2, %3"
                 : "=&v"(d) : "v"(a), "v"(b), "v"(c));
    return d;
}
#define MFMA16(a, b, c) mfma16_asm(a, b, c)
#endif

// ---------------------------------------------------------------------------
// Kernel 1: FUSED QKV projection (unchanged from R3 -- measured ~5us).
// grid (16, 64), block 256.
// ---------------------------------------------------------------------------
__global__ __launch_bounds__(256)
void proj_kernel(const float* __restrict__ x,
                 const float* __restrict__ Wq,
                 const float* __restrict__ Wk,
                 const float* __restrict__ Wv,
                 unsigned short* __restrict__ Qt,
                 unsigned short* __restrict__ Kt,
                 unsigned short* __restrict__ Vt) {
    const int lane = threadIdx.x & 63;
    const int wv   = threadIdx.x >> 6;
    const int m = lane & 15, q = lane >> 4;
    const int bh = blockIdx.y, b = bh >> 3, h = bh & 7;
    const int n0 = (blockIdx.x * 4 + wv) * 16;

    const size_t wrow_off = ((size_t)((h * B_ + b) * DK + m)) * D_;  // A row m
    const float* Wqr = Wq + wrow_off;
    const float* Wkr = Wk + wrow_off;
    const float* Wvr = Wv + wrow_off;
    const float* xb = x + (size_t)b * D_ * L_ + n0 + m;

    f4 aQ = {0.f, 0.f, 0.f, 0.f}, aK = {0.f, 0.f, 0.f, 0.f}, aV = {0.f, 0.f, 0.f, 0.f};
#pragma unroll
    for (int kb = 0; kb < 8; ++kb) {
        const int k4 = kb * 16 + q * 4;

        const float* xc = xb + (size_t)k4 * L_;
        float b0 = xc[0], b1 = xc[L_], b2 = xc[2 * L_], b3 = xc[3 * L_];
        s4 bf = pack4(b0, b1, b2, b3);

        float4 wq = *(const float4*)(Wqr + k4);
        float4 wk = *(const float4*)(Wkr + k4);
        float4 wv4 = *(const float4*)(Wvr + k4);
        s4 fq = pack4(wq.x, wq.y, wq.z, wq.w);
        s4 fk = pack4(wk.x, wk.y, wk.z, wk.w);
        s4 fv = pack4(wv4.x, wv4.y, wv4.z, wv4.w);

        aQ = MFMA16(fq, bf, aQ);
        aK = MFMA16(fk, bf, aK);
        aV = MFMA16(fv, bf, aV);
    }

    // Epilogues.  C layout: [row = q*4 + r][col = m] (row = dk, col = l).
    uint2 uq;
    uq.x = pack2(aQ[0], aQ[1]);
    uq.y = pack2(aQ[2], aQ[3]);
    *(uint2*)(Qt + ((size_t)bh * L_ + n0 + m) * DK + q * 4) = uq;

    const float sc = 0.25f * 1.4426950408889634f;   // 1/sqrt(Dk) * log2(e)
    uint2 uk;
    uk.x = pack2(aK[0] * sc, aK[1] * sc);
    uk.y = pack2(aK[2] * sc, aK[3] * sc);
    *(uint2*)(Kt + ((size_t)bh * L_ + n0 + m) * DK + q * 4) = uk;

    unsigned short* vp = Vt + ((size_t)bh * DK + q * 4) * L_ + n0 + m;
    vp[0]      = f2bf(aV[0]); vp[L_]     = f2bf(aV[1]);
    vp[2 * L_] = f2bf(aV[2]); vp[3 * L_] = f2bf(aV[3]);
}

// ---------------------------------------------------------------------------
// Kernel 2 (NEW STRUCTURE): attention with LDS-RESIDENT Q/V.
// R7/R8 counters: 1640 cy/iter/wave, FETCH 19.5MB (3x working set), all
// pipes idle -> per-iteration serialized HBM-latency loads were the wall.
// Fix: block = (jg, bh) stages this head's whole Q (32KB) + V (32KB) into
// LDS once (coalesced, fragment-order: frag[it][lane] = consecutive 8B =
// conflict-free stride-1), then 16 waves each own a 16-wide j-tile over the
// FULL i range from LDS.  No cross-wave merge, no global loads in the loop.
// Writes normalized head tile Ht[b][d][j] (bf16).  grid (4, 64), block 1024.
// ---------------------------------------------------------------------------
__global__ __launch_bounds__(1024)
void attn_kernel(const unsigned short* __restrict__ Qt,
                 const unsigned short* __restrict__ Kt,
                 const unsigned short* __restrict__ Vt,
                 unsigned short* __restrict__ Ht) {
    const int tid  = threadIdx.x;
    const int lane = tid & 63;
    const int wid  = tid >> 6;              // 0..15
    const int m = lane & 15, q = lane >> 4;
    const int jg = blockIdx.x, bh = blockIdx.y;

    // frag[it][lane]: Qf -> Q[it*16+m][q*4+j], Vf -> V[m][it*16+q*4+j]
    __shared__ s4 Qf[64 * 64];              // 32 KB
    __shared__ s4 Vf[64 * 64];              // 32 KB

    const unsigned short* Qg = Qt + (size_t)bh * L_ * DK;
    const unsigned short* Vg = Vt + (size_t)bh * DK * L_;
#pragma unroll
    for (int c = 0; c < 4; ++c) {
        const int e  = c * 1024 + tid;
        const int it = e >> 6;
        const int em = e & 15;
        const int eq = (e >> 4) & 3;
        // Q[l = it*16+em][k = eq*4 ..+4]  (512B contiguous per wave, permuted)
        Qf[e] = *(const s4*)(Qg + (size_t)(it * 16 + em) * DK + eq * 4);
        // V[v = em][i = it*16+eq*4 ..+4]
        Vf[e] = *(const s4*)(Vg + (size_t)em * L_ + it * 16 + eq * 4);
    }

    const int j0 = jg * 256 + wid * 16;
    s4 bk = *(const s4*)(Kt + ((size_t)bh * L_ + j0 + m) * DK + q * 4);

    __syncthreads();

    f4 O = {0.f, 0.f, 0.f, 0.f};
    float ls = 0.f;
#pragma unroll 8
    for (int it = 0; it < 64; ++it) {
        s4 aq = Qf[it * 64 + lane];
        s4 av = Vf[it * 64 + lane];

        f4 z = {0.f, 0.f, 0.f, 0.f};
        f4 S = MFMA16(aq, bk, z);       // S[it*16+q*4+r][j0+m]  (*log2e)

        float p0 = fexp2(S[0]), p1 = fexp2(S[1]);
        float p2 = fexp2(S[2]), p3 = fexp2(S[3]);
        ls += (p0 + p1) + (p2 + p3);

        s4 pb;
        pb[0] = (short)f2bf(p0); pb[1] = (short)f2bf(p1);
        pb[2] = (short)f2bf(p2); pb[3] = (short)f2bf(p3);

        O = MFMA16(av, pb, O);          // O[v=q*4+r][j0+m] += V*P
    }

    // sum the 4 q-group partial column-sums (rows of S are split across q)
    ls += __shfl_xor(ls, 16, 64);
    ls += __shfl_xor(ls, 32, 64);
    const float inv = 1.f / ls;

    // Ht[b][d = h*16 + q*4 + r][j = j0+m]; bh*16 = b*128 + h*16
    unsigned short* hp = Ht + ((size_t)bh * DK + q * 4) * L_ + j0 + m;
    hp[0]      = f2bf(O[0] * inv); hp[L_]     = f2bf(O[1] * inv);
    hp[2 * L_] = f2bf(O[2] * inv); hp[3 * L_] = f2bf(O[3] * inv);
}

// ---------------------------------------------------------------------------
// Kernel 3: output projection out[b] = Wo[b] @ Ht[b].  Clone of the proven
// phase-2 pattern; Ht bf16 bits placed directly into B-fragments (no cvt).
// grid (32, 8), block 1024: wave wid -> (oc = wid&7, jt = wid>>3).
// ---------------------------------------------------------------------------
__global__ __launch_bounds__(1024)
void outproj_kernel(const unsigned short* __restrict__ Ht,
                    const float* __restrict__ Wo,
                    float* __restrict__ out) {
    const int lane = threadIdx.x & 63;
    const int wid  = threadIdx.x >> 6;
    const int m = lane & 15, q = lane >> 4;
    const int b = blockIdx.y;
    const int oc = wid & 7, jt = wid >> 3;
    const int j16 = blockIdx.x * 32 + jt * 16;
    const int o0 = oc * 16;

    const float* Wrow = Wo + ((size_t)b * D_ + o0 + m) * D_;   // A row m
    const unsigned short* Hb = Ht + (size_t)b * D_ * L_ + j16 + m;

    f4 acc = {0.f, 0.f, 0.f, 0.f};
#pragma unroll
    for (int kb = 0; kb < 8; ++kb) {
        const int k4 = kb * 16 + q * 4;
        float4 wf = *(const float4*)(Wrow + k4);
        s4 a = pack4(wf.x, wf.y, wf.z, wf.w);

        const unsigned short* hp = Hb + (size_t)k4 * L_;
        s4 bb;                          // B[k][n=j] = Ht[d=k][j]
        bb[0] = (short)hp[0];
        bb[1] = (short)hp[L_];
        bb[2] = (short)hp[2 * L_];
        bb[3] = (short)hp[3 * L_];
        acc = MFMA16(a, bb, acc);
    }

    float* op = out + ((size_t)b * D_ + o0 + q * 4) * L_ + j16 + m;
    op[0]      = acc[0]; op[L_]     = acc[1];
    op[2 * L_] = acc[2]; op[3 * L_] = acc[3];
}

// ---------------------------------------------------------------------------
extern "C" void kernel_launch(void* const* d_in, const int* in_sizes, int n_in,
                              void* d_out, int out_size, void* d_ws, size_t ws_size,
                              hipStream_t stream) {
    const float* x  = (const float*)d_in[0];
    const float* Wq = (const float*)d_in[1];
    const float* Wk = (const float*)d_in[2];
    const float* Wv = (const float*)d_in[3];
    const float* Wo = (const float*)d_in[4];
    float* out = (float*)d_out;

    const size_t SEG = (size_t)B_ * NH * DK * L_;   // 1,048,576 elements
    unsigned short* Qt = (unsigned short*)d_ws;     // bf16 [bh][l][k], 2 MB
    unsigned short* Kt = Qt + SEG;                  // bf16 [bh][j][k], 2 MB
    unsigned short* Vt = Kt + SEG;                  // bf16 [bh][v][i], 2 MB
    unsigned short* Ht = Vt + SEG;                  // bf16 [b][d][j],  2 MB

    proj_kernel<<<dim3(16, B_ * NH), 256, 0, stream>>>(x, Wq, Wk, Wv, Qt, Kt, Vt);
    attn_kernel<<<dim3(4, B_ * NH), 1024, 0, stream>>>(Qt, Kt, Vt, Ht);
    outproj_kernel<<<dim3(32, B_), 1024, 0, stream>>>(Ht, Wo, out);
}